// Round 5
// baseline (254.519 us; speedup 1.0000x reference)
//
#include <hip/hip_runtime.h>
#include <math.h>

#define Bz 32
#define Sz 4096
#define Hz 32
#define Gz 2
#define Dz 128
#define HIDz 4096
#define QKVz 4608
#define NCHc 32   // combine chunks per (b,g); chunk = 4 strided units

static __device__ __forceinline__ void fma4(float4& a, float s, const float4& v) {
  a.x = fmaf(s, v.x, a.x);
  a.y = fmaf(s, v.y, a.y);
  a.z = fmaf(s, v.z, a.z);
  a.w = fmaf(s, v.w, a.w);
}

// ---------------- split-K GEMM partial: part[kt][b][j] = sum_{k in chunk} X[b][k]*W[k][j]
__global__ __launch_bounds__(256) void gemm_partial(
    const float* __restrict__ X, const float* __restrict__ W,
    float* __restrict__ part, int K, int N, int KH) {
  extern __shared__ float hl[];  // [32][KH+4]
  const int stride = KH + 4;
  const int t = threadIdx.x;
  const int k0 = blockIdx.y * KH;
  const int cols4 = KH >> 2;
  const int total4 = Bz * cols4;
  for (int fi = t; fi < total4; fi += 256) {
    const int row = fi / cols4;
    const int c4 = fi - row * cols4;
    const float4 v = *(const float4*)&X[(size_t)row * K + k0 + c4 * 4];
    *(float4*)&hl[row * stride + c4 * 4] = v;
  }
  __syncthreads();
  const int jl = t & 31;
  const int b0 = (t >> 5) * 4;
  const int j = blockIdx.x * 128 + jl * 4;
  float4 acc[4];
  #pragma unroll
  for (int i = 0; i < 4; i++) acc[i] = make_float4(0.f, 0.f, 0.f, 0.f);
  #pragma unroll 4
  for (int kk = 0; kk < KH; kk += 4) {
    const float4 w0 = *(const float4*)&W[(size_t)(k0 + kk + 0) * N + j];
    const float4 w1 = *(const float4*)&W[(size_t)(k0 + kk + 1) * N + j];
    const float4 w2 = *(const float4*)&W[(size_t)(k0 + kk + 2) * N + j];
    const float4 w3 = *(const float4*)&W[(size_t)(k0 + kk + 3) * N + j];
    #pragma unroll
    for (int bi = 0; bi < 4; bi++) {
      const float4 hb = *(const float4*)&hl[(b0 + bi) * stride + kk];
      fma4(acc[bi], hb.x, w0);
      fma4(acc[bi], hb.y, w1);
      fma4(acc[bi], hb.z, w2);
      fma4(acc[bi], hb.w, w3);
    }
  }
  #pragma unroll
  for (int bi = 0; bi < 4; bi++) {
    *(float4*)&part[((size_t)blockIdx.y * Bz + b0 + bi) * N + j] = acc[bi];
  }
}

// ---------------- reduce QKV partials + bias, RoPE, emit qrot (pre-scaled), krot, vnew
__global__ __launch_bounds__(256) void qkv_finish(
    const float* __restrict__ part, const float* __restrict__ bias,
    const int* __restrict__ positions, int KT,
    float* __restrict__ qrot, float* __restrict__ krot, float* __restrict__ vnew) {
  const int t = threadIdx.x;
  const int b = blockIdx.x;
  const int head = blockIdx.y * 4 + (t >> 6);
  const int tp = t & 63;
  const int j0 = head * Dz + tp * 2;
  float s0 = bias[j0];
  float s1 = bias[j0 + 1];
  for (int kt = 0; kt < KT; kt++) {
    const float2 p = *(const float2*)&part[((size_t)kt * Bz + b) * QKVz + j0];
    s0 += p.x;
    s1 += p.y;
  }
  float o0 = s0, o1 = s1;
  if (head < Hz + Gz && tp < 32) {
    const float invf = exp2f(-(float)tp * (13.287712379549449f / 32.0f));
    const float a = (float)positions[b] * invf;
    float sn, cs;
    sincosf(a, &sn, &cs);
    o0 = s0 * cs - s1 * sn;
    o1 = s1 * cs + s0 * sn;
  }
  if (head < Hz) {
    const float sc = 0.08838834764831845f;
    float2 o = make_float2(o0 * sc, o1 * sc);
    *(float2*)&qrot[((size_t)b * Hz + head) * Dz + tp * 2] = o;
  } else if (head < Hz + Gz) {
    float2 o = make_float2(o0, o1);
    *(float2*)&krot[((size_t)b * Gz + (head - Hz)) * Dz + tp * 2] = o;
  } else {
    float2 o = make_float2(s0, s1);
    *(float2*)&vnew[((size_t)b * Gz + (head - Hz - Gz)) * Dz + tp * 2] = o;
  }
}

// ---------------- flash unit (strided rows): wave-unit u = bx*4+w owns rows {u + 128k, k<32}.
// Lane (hq,sq): QK = 4 heads x 2 k-slots (sq, sq+16); PV = 4 heads x 8 d.
// All blocks do equal work; high k-half skipped when nv <= 16.
// grid (32, G, B), block 256, 18.2 KB LDS -> 8 blocks/CU.
__global__ __launch_bounds__(256, 8) void attn_unit(
    const float* __restrict__ qrot, const float* __restrict__ kcache,
    const float* __restrict__ vcache, const float* __restrict__ krot,
    const float* __restrict__ vnew, const int* __restrict__ positions,
    float* __restrict__ mbuf, float* __restrict__ lbuf, float* __restrict__ pacc) {
  __shared__ float smem[4544];
  // qs = smem[0..2112) (16x132), aliased as Aw in combine; plw[w]=smem[2112+w*576) (16x36);
  // ml = smem[4416..4544): [w*32 + {m:h, l:16+h}]
  float* qs = smem;
  const int g = blockIdx.y, b = blockIdx.z;
  const int pos = positions[b];
  const int t = threadIdx.x;
  for (int i = t; i < 16 * 32; i += 256) {
    const int row = i >> 5, c4 = i & 31;
    *(float4*)&qs[row * 132 + c4 * 4] =
        *(const float4*)&qrot[((size_t)b * Hz + g * 16 + row) * Dz + c4 * 4];
  }
  __syncthreads();

  const int w = t >> 6;
  const int lane = t & 63;
  const int hq = lane >> 4;
  const int sq = lane & 15;
  float* plw = smem + 2112 + w * 576;
  const int u = blockIdx.x * 4 + w;                       // unit in [0,128)
  const int nv = (u <= pos) ? ((pos - u) >> 7) + 1 : 0;   // valid k-slots (<=32)

  float m_run[4], l_run[4];
  float4 A[4][2];
  #pragma unroll
  for (int i = 0; i < 4; i++) {
    m_run[i] = -1e30f;
    l_run[i] = 0.f;
    A[i][0] = make_float4(0.f, 0.f, 0.f, 0.f);
    A[i][1] = make_float4(0.f, 0.f, 0.f, 0.f);
  }

  if (nv > 0) {
    const bool hi = nv > 16;
    const float* krow_new = &krot[((size_t)b * Gz + g) * Dz];
    const float* vrow_new = &vnew[((size_t)b * Gz + g) * Dz];
    const size_t kvb = ((size_t)b * Sz) * (Gz * Dz) + (size_t)g * Dz;

    const int sg0 = u + sq * 128;           // k = sq
    const int sg1 = u + (sq + 16) * 128;    // k = sq+16
    const float* kp0 = (sg0 >= pos) ? krow_new : &kcache[kvb + (size_t)sg0 * (Gz * Dz)];
    const float* kp1 = (sg1 >= pos) ? krow_new : &kcache[kvb + (size_t)sg1 * (Gz * Dz)];
    float acc[4][2];
    #pragma unroll
    for (int i = 0; i < 4; i++) { acc[i][0] = 0.f; acc[i][1] = 0.f; }

#define QK1(buf, c)                                                       \
    { _Pragma("unroll") for (int j = 0; j < 4; ++j) {                     \
        _Pragma("unroll") for (int i = 0; i < 4; ++i) {                   \
          const float4 q = *(const float4*)&qs[(hq * 4 + i) * 132 + ((c) * 4 + j) * 4]; \
          acc[i][0] = fmaf(q.x, buf[j].x, fmaf(q.y, buf[j].y, fmaf(q.z, buf[j].z, fmaf(q.w, buf[j].w, acc[i][0])))); } } }
#define QK2(buf, c)                                                       \
    { _Pragma("unroll") for (int j = 0; j < 4; ++j) {                     \
        _Pragma("unroll") for (int i = 0; i < 4; ++i) {                   \
          const float4 q = *(const float4*)&qs[(hq * 4 + i) * 132 + ((c) * 4 + j) * 4]; \
          acc[i][0] = fmaf(q.x, buf[j][0].x, fmaf(q.y, buf[j][0].y, fmaf(q.z, buf[j][0].z, fmaf(q.w, buf[j][0].w, acc[i][0])))); \
          acc[i][1] = fmaf(q.x, buf[j][1].x, fmaf(q.y, buf[j][1].y, fmaf(q.z, buf[j][1].z, fmaf(q.w, buf[j][1].w, acc[i][1])))); } } }
    if (hi) {
      float4 ka[4][2], kb[4][2];
#define BK2(buf, c)                                                       \
      { _Pragma("unroll") for (int j = 0; j < 4; ++j) {                   \
          buf[j][0] = *(const float4*)&kp0[((c) * 4 + j) * 4];            \
          buf[j][1] = *(const float4*)&kp1[((c) * 4 + j) * 4]; } }
      BK2(ka, 0); BK2(kb, 1);
      QK2(ka, 0); BK2(ka, 2);
      QK2(kb, 1); BK2(kb, 3);
      QK2(ka, 2); BK2(ka, 4);
      QK2(kb, 3); BK2(kb, 5);
      QK2(ka, 4); BK2(ka, 6);
      QK2(kb, 5); BK2(kb, 7);
      QK2(ka, 6); QK2(kb, 7);
#undef BK2
      if (sq + 16 >= nv) {
        #pragma unroll
        for (int i = 0; i < 4; ++i) acc[i][1] = -1e30f;
      }
    } else {
      float4 ka[4], kb[4];
#define BK1(buf, c)                                                       \
      { _Pragma("unroll") for (int j = 0; j < 4; ++j)                     \
          buf[j] = *(const float4*)&kp0[((c) * 4 + j) * 4]; }
      BK1(ka, 0); BK1(kb, 1);
      QK1(ka, 0); BK1(ka, 2);
      QK1(kb, 1); BK1(kb, 3);
      QK1(ka, 2); BK1(ka, 4);
      QK1(kb, 3); BK1(kb, 5);
      QK1(ka, 4); BK1(ka, 6);
      QK1(kb, 5); BK1(kb, 7);
      QK1(ka, 6); QK1(kb, 7);
#undef BK1
      if (sq >= nv) {
        #pragma unroll
        for (int i = 0; i < 4; ++i) acc[i][0] = -1e30f;
      }
      #pragma unroll
      for (int i = 0; i < 4; ++i) acc[i][1] = -1e30f;
    }
#undef QK1
#undef QK2
    // ---- softmax (within 16-lane segment); k-slot layout plw[h][k], k = sq / sq+16
    #pragma unroll
    for (int i = 0; i < 4; ++i) {
      float tm = fmaxf(acc[i][0], acc[i][1]);
      tm = fmaxf(tm, __shfl_xor(tm, 1, 16));
      tm = fmaxf(tm, __shfl_xor(tm, 2, 16));
      tm = fmaxf(tm, __shfl_xor(tm, 4, 16));
      tm = fmaxf(tm, __shfl_xor(tm, 8, 16));
      m_run[i] = tm;
      const float p0 = __expf(acc[i][0] - tm);
      const float p1 = __expf(acc[i][1] - tm);
      float ts = p0 + p1;
      ts += __shfl_xor(ts, 1, 16);
      ts += __shfl_xor(ts, 2, 16);
      ts += __shfl_xor(ts, 4, 16);
      ts += __shfl_xor(ts, 8, 16);
      l_run[i] = ts;
      plw[(hq * 4 + i) * 36 + sq] = p0;
      if (hi) plw[(hq * 4 + i) * 36 + 16 + sq] = p1;
    }
    // ---- PV: lane = 4 heads x 8 d; groups of 4 k-slots, dbuf bursts
    float4 va[4][2], vb[4][2];
#define BV(buf, rg)                                                       \
    { _Pragma("unroll") for (int r = 0; r < 4; ++r) {                     \
        const int sg = u + ((rg) * 4 + r) * 128;                          \
        const float* vp = (sg >= pos) ? vrow_new : &vcache[kvb + (size_t)sg * (Gz * Dz)]; \
        buf[r][0] = *(const float4*)&vp[sq * 8];                          \
        buf[r][1] = *(const float4*)&vp[sq * 8 + 4]; } }
#define PVC(buf, rg)                                                      \
    { float4 pf[4];                                                       \
      _Pragma("unroll") for (int i = 0; i < 4; ++i)                       \
        pf[i] = *(const float4*)&plw[(hq * 4 + i) * 36 + (rg) * 4];       \
      _Pragma("unroll") for (int r = 0; r < 4; ++r) {                     \
        _Pragma("unroll") for (int i = 0; i < 4; ++i) {                   \
          const float pr = ((const float*)&pf[i])[r];                     \
          fma4(A[i][0], pr, buf[r][0]);                                   \
          fma4(A[i][1], pr, buf[r][1]); } } }
    BV(va, 0); BV(vb, 1);
    PVC(va, 0); BV(va, 2);
    PVC(vb, 1); BV(vb, 3);
    PVC(va, 2);
    if (hi) {
      BV(va, 4); PVC(vb, 3);
      BV(vb, 5); PVC(va, 4);
      BV(va, 6); PVC(vb, 5);
      BV(vb, 7); PVC(va, 6);
      PVC(vb, 7);
    } else {
      PVC(vb, 3);
    }
#undef BV
#undef PVC
  }

  // ---- in-block combine: serial accumulate through one 16x132 buffer (aliases qs)
  __syncthreads();
  float* ml = smem + 4416;
  if (sq == 0) {
    #pragma unroll
    for (int i = 0; i < 4; ++i) {
      ml[w * 32 + hq * 4 + i] = m_run[i];
      ml[w * 32 + 16 + hq * 4 + i] = l_run[i];
    }
  }
  __syncthreads();
  float ew[4];
  #pragma unroll
  for (int i = 0; i < 4; ++i) {
    const int h = hq * 4 + i;
    const float ms = fmaxf(fmaxf(ml[h], ml[32 + h]), fmaxf(ml[64 + h], ml[96 + h]));
    ew[i] = __expf(m_run[i] - ms);
  }
  float* Aw = smem;  // 16 x 132
  for (int step = 0; step < 4; ++step) {
    if (w == step) {
      #pragma unroll
      for (int i = 0; i < 4; ++i) {
        const int h = hq * 4 + i;
        if (step == 0) {
          float4 x0 = make_float4(ew[i] * A[i][0].x, ew[i] * A[i][0].y,
                                  ew[i] * A[i][0].z, ew[i] * A[i][0].w);
          float4 x1 = make_float4(ew[i] * A[i][1].x, ew[i] * A[i][1].y,
                                  ew[i] * A[i][1].z, ew[i] * A[i][1].w);
          *(float4*)&Aw[h * 132 + sq * 8] = x0;
          *(float4*)&Aw[h * 132 + sq * 8 + 4] = x1;
        } else {
          float4 c0 = *(const float4*)&Aw[h * 132 + sq * 8];
          float4 c1 = *(const float4*)&Aw[h * 132 + sq * 8 + 4];
          fma4(c0, ew[i], A[i][0]);
          fma4(c1, ew[i], A[i][1]);
          *(float4*)&Aw[h * 132 + sq * 8] = c0;
          *(float4*)&Aw[h * 132 + sq * 8 + 4] = c1;
        }
      }
    }
    __syncthreads();
  }
  const size_t cb = (size_t)(b * Gz + g) * NCHc + blockIdx.x;
  for (int o = t; o < 512; o += 256) {
    const int h = o >> 5, d4c = o & 31;
    *(float4*)&pacc[cb * 2048 + (size_t)h * Dz + d4c * 4] =
        *(const float4*)&Aw[h * 132 + d4c * 4];
  }
  if (t < 16) {
    const int h = t;
    const float m0 = ml[h], m1 = ml[32 + h], m2 = ml[64 + h], m3 = ml[96 + h];
    const float ms = fmaxf(fmaxf(m0, m1), fmaxf(m2, m3));
    const float l = __expf(m0 - ms) * ml[16 + h] + __expf(m1 - ms) * ml[48 + h] +
                    __expf(m2 - ms) * ml[80 + h] + __expf(m3 - ms) * ml[112 + h];
    mbuf[cb * 16 + h] = ms;
    lbuf[cb * 16 + h] = l;
  }
}

// ---------------- combine chunk partials -> ctx (B, H*D); all NCHc chunks always live
__global__ __launch_bounds__(512) void attn_combine(
    const float* __restrict__ mbuf, const float* __restrict__ lbuf,
    const float* __restrict__ pacc, const int* __restrict__ positions,
    float* __restrict__ ctx) {
  const int bg = blockIdx.x;
  const int b = bg >> 1, g = bg & 1;
  const int t = threadIdx.x;
  const int h = t >> 5, dg = t & 31;
  const size_t mlb = (size_t)bg * NCHc * 16 + h;
  float mstar = -1e30f;
  for (int c = 0; c < NCHc; c++) mstar = fmaxf(mstar, mbuf[mlb + c * 16]);
  float lsum = 0.f;
  float4 A = make_float4(0.f, 0.f, 0.f, 0.f);
  for (int c = 0; c < NCHc; c++) {
    const float wv = __expf(mbuf[mlb + c * 16] - mstar);
    lsum += wv * lbuf[mlb + c * 16];
    const float4 p = *(const float4*)&pacc[((size_t)bg * NCHc + c) * 2048 + (size_t)h * Dz + dg * 4];
    fma4(A, wv, p);
  }
  const float inv = 1.0f / lsum;
  float4 o = make_float4(A.x * inv, A.y * inv, A.z * inv, A.w * inv);
  *(float4*)&ctx[(size_t)b * (Hz * Dz) + (g * 16 + h) * Dz + dg * 4] = o;
}

// ---------------- reduce dense partials -> out
__global__ __launch_bounds__(256) void reduce_out(
    const float* __restrict__ part, float* __restrict__ out, int KT) {
  const int idx = blockIdx.x * 256 + threadIdx.x;
  const int b = idx >> 12;
  const int j = idx & 4095;
  float s = 0.f;
  for (int kt = 0; kt < KT; kt++) s += part[((size_t)kt * Bz + b) * HIDz + j];
  out[idx] = s;
}

extern "C" void kernel_launch(void* const* d_in, const int* in_sizes, int n_in,
                              void* d_out, int out_size, void* d_ws, size_t ws_size,
                              hipStream_t stream) {
  const float* hidden = (const float*)d_in[0];
  const int* positions = (const int*)d_in[1];
  const float* kcache = (const float*)d_in[2];
  const float* vcache = (const float*)d_in[3];
  const float* Wqkv = (const float*)d_in[4];
  const float* bqkv = (const float*)d_in[5];
  const float* Wd = (const float*)d_in[6];
  float* out = (float*)d_out;

  auto need = [](int KT) -> size_t {
    return (size_t)KT * Bz * QKVz
         + (size_t)Bz * Hz * Dz
         + (size_t)Bz * Gz * Dz * 2
         + (size_t)Bz * Gz * NCHc * 16 * 2
         + (size_t)Bz * Gz * NCHc * 2048
         + (size_t)Bz * HIDz;
  };
  int KT = 32;
  if (need(32) * sizeof(float) > ws_size) KT = 16;
  const int KH = HIDz / KT;

  float* w = (float*)d_ws;
  float* p1 = w;    w += (size_t)KT * Bz * QKVz;
  float* qrot = w;  w += (size_t)Bz * Hz * Dz;
  float* krot = w;  w += (size_t)Bz * Gz * Dz;
  float* vnew = w;  w += (size_t)Bz * Gz * Dz;
  float* mbuf = w;  w += (size_t)Bz * Gz * NCHc * 16;
  float* lbuf = w;  w += (size_t)Bz * Gz * NCHc * 16;
  float* pacc = w;  w += (size_t)Bz * Gz * NCHc * 2048;
  float* ctx = w;

  const size_t smem = (size_t)Bz * (KH + 4) * sizeof(float);

  gemm_partial<<<dim3(QKVz / 128, KT), 256, smem, stream>>>(hidden, Wqkv, p1, HIDz, QKVz, KH);
  qkv_finish<<<dim3(Bz, 9), 256, 0, stream>>>(p1, bqkv, positions, KT, qrot, krot, vnew);
  attn_unit<<<dim3(NCHc, Gz, Bz), 256, 0, stream>>>(qrot, kcache, vcache, krot, vnew, positions,
                                                    mbuf, lbuf, pacc);
  attn_combine<<<dim3(Bz * Gz), 512, 0, stream>>>(mbuf, lbuf, pacc, positions, ctx);
  gemm_partial<<<dim3(HIDz / 128, KT), 256, smem, stream>>>(ctx, Wd, p1, Hz * Dz, HIDz, KH);
  reduce_out<<<dim3(Bz * HIDz / 256), 256, 0, stream>>>(p1, out, KT);
}